// Round 5
// baseline (501.656 us; speedup 1.0000x reference)
//
#include <hip/hip_runtime.h>
#include <hip/hip_bf16.h>
#include <hip/hip_fp16.h>
#include <stdint.h>

#define M_DIM 4096   // B*S = 2*2048
#define N_DIM 4096   // O
#define K_DIM 4096   // I
#define GROUPSZ 128
#define MAXQ 15.0f

#define BM 256
#define BN 256
#define BK 64
#define T_TILES (K_DIM / BK)   // 64

typedef __attribute__((ext_vector_type(8))) short short8;
typedef __attribute__((ext_vector_type(4))) float f32x4;

// ---------------- quant: groupwise asymmetric fake-quant, f32 -> bf16 ----------------
__global__ __launch_bounds__(256) void quant_kernel(
    const float* __restrict__ weight, const float* __restrict__ value,
    const float* __restrict__ min_scale, const float* __restrict__ max_scale,
    __hip_bfloat16* __restrict__ wq)
{
    const int tid  = threadIdx.x;
    const int wave = tid >> 6;
    const int lane = tid & 63;
    const long g    = (long)blockIdx.x * 4 + wave;
    const long base = g * GROUPSZ + lane * 2;

    const float2 w = *(const float2*)(weight + base);
    const float2 v = *(const float2*)(value  + base);

    float mn = fminf(w.x, w.y);
    float mx = fmaxf(w.x, w.y);
#pragma unroll
    for (int off = 32; off >= 1; off >>= 1) {
        mn = fminf(mn, __shfl_xor(mn, off, 64));
        mx = fmaxf(mx, __shfl_xor(mx, off, 64));
    }
    mn = fminf(mn, 0.0f);
    mx = fmaxf(mx, 0.0f);

    const float ms = fminf(fmaxf(min_scale[g], -1.0f), 0.0f) + 1.0f;
    const float xs = fminf(fmaxf(max_scale[g], -1.0f), 0.0f) + 1.0f;
    float wmin = mn * ms;
    float wmax = mx * xs;
    if (wmin == 0.0f && wmax == 0.0f) { wmin = -1.0f; wmax = 1.0f; }

    const float scale = (float)(_Float16)((wmax - wmin) / MAXQ);
    const float zp    = rintf(-wmin / scale);

    const float q0 = fminf(fmaxf(rintf(w.x / scale + v.x) + zp, 0.0f), MAXQ);
    const float q1 = fminf(fmaxf(rintf(w.y / scale + v.y) + zp, 0.0f), MAXQ);
    const float o0 = scale * (q0 - zp);
    const float o1 = scale * (q1 - zp);

    __hip_bfloat162 o;
    o.x = __float2bfloat16(o0);
    o.y = __float2bfloat16(o1);
    *(__hip_bfloat162*)(wq + base) = o;
}

// ---------------- x cast: f32 -> bf16, 8 elems/thread ----------------
__global__ __launch_bounds__(256) void cast_kernel(
    const float* __restrict__ x, __hip_bfloat16* __restrict__ xb)
{
    const long i = ((long)blockIdx.x * 256 + threadIdx.x) * 8;
    const float4 a = *(const float4*)(x + i);
    const float4 b = *(const float4*)(x + i + 4);
    union { short8 s; __hip_bfloat16 h[8]; } u;
    u.h[0] = __float2bfloat16(a.x);
    u.h[1] = __float2bfloat16(a.y);
    u.h[2] = __float2bfloat16(a.z);
    u.h[3] = __float2bfloat16(a.w);
    u.h[4] = __float2bfloat16(b.x);
    u.h[5] = __float2bfloat16(b.y);
    u.h[6] = __float2bfloat16(b.z);
    u.h[7] = __float2bfloat16(b.w);
    *(short8*)(xb + i) = u.s;
}

// ---------------- GEMM: 256x256, BK=64, 8 waves, lean register-pipelined 4-phase ----------------
// Phase = (m-half x kk-half), 16 independent MFMA each. Each phase prefetches the
// NEXT phase's ds_reads before its MFMA (counted lgkmcnt, never 0) so the LDS pipe
// drains under the matrix pipe. 3 barriers/K-tile. Peak fragment liveness 64 VGPR.
__global__ __launch_bounds__(512, 2) void gemm_kernel(
    const __hip_bfloat16* __restrict__ A,   // [M][K] bf16 (x)
    const __hip_bfloat16* __restrict__ B,   // [N][K] bf16 (wq)
    const float* __restrict__ bias,
    float* __restrict__ C)                  // [M][N] f32
{
    __shared__ __align__(16) char lds[131072];
    // A buf c: [c*32768, +32768); B buf c: [65536 + c*32768, +32768)
    // row r at r*128 bytes; 16B slot s holds logical slot s ^ (r&7).

    const int tid  = threadIdx.x;
    const int lane = tid & 63;
    const int wv   = tid >> 6;
    const int wm   = wv >> 2;          // 2 (M) x 4 (N) wave grid
    const int wn   = wv & 3;

    const int bid = blockIdx.x;
    const int swz = (bid & 7) * (gridDim.x >> 3) + (bid >> 3);
    const int brow = (swz >> 4) * BM;
    const int bcol = (swz & 15) * BN;

    const int stg_r = tid >> 3;
    const int cc    = ((tid & 7) ^ (stg_r & 7)) * 8;

#define STAGE(XP, rowbase, h, tau, ldsbase)                                         \
    { _Pragma("unroll")                                                             \
      for (int inst = 0; inst < 2; ++inst) {                                        \
        const __hip_bfloat16* g = (XP) +                                            \
            (size_t)((rowbase) + (h) * 128 + inst * 64 + stg_r) * K_DIM +           \
            (tau) * 64 + cc;                                                        \
        __builtin_amdgcn_global_load_lds(                                           \
            (const __attribute__((address_space(1))) void*)g,                       \
            (__attribute__((address_space(3))) void*)(lds + (ldsbase) +             \
                (h) * 16384 + inst * 8192 + (wv << 10)),                            \
            16, 0, 0);                                                              \
      } }

    const int ro = lane & 15;
    const int hi = lane >> 4;
    const int slot0 = ((0 + hi) ^ (ro & 7)) << 4;
    const int slot1 = ((4 + hi) ^ (ro & 7)) << 4;
    const int rbA = (wm * 128 + ro) * 128;
    const int rbB = (wn * 64  + ro) * 128;

    f32x4 acc[8][4] = {};
    short8 B0a[4], Aaa[4], B0b[4], Aab[4];   // cross-tile rotating prefetch sets

#define MFMA16(M0, Bf, Af)                                                          \
    { _Pragma("unroll")                                                             \
      for (int n = 0; n < 4; ++n) {                                                 \
        _Pragma("unroll")                                                           \
        for (int mm = 0; mm < 4; ++mm)                                              \
            acc[(M0) + mm][n] = __builtin_amdgcn_mfma_f32_16x16x32_bf16(            \
                Af[mm], Bf[n], acc[(M0) + mm][n], 0, 0, 0);                         \
      } }

#define RD4(dst, base, M0, S)                                                       \
    dst[0] = *(const short8*)((base) + ((M0) + 0) * 2048 + (S));                    \
    dst[1] = *(const short8*)((base) + ((M0) + 1) * 2048 + (S));                    \
    dst[2] = *(const short8*)((base) + ((M0) + 2) * 2048 + (S));                    \
    dst[3] = *(const short8*)((base) + ((M0) + 3) * 2048 + (S));

    // prologue: stage B(0), A(0), B(1); wait; prefetch tile0 P1 operands
    STAGE(B, bcol, 0, 0, 65536);
    STAGE(B, bcol, 1, 0, 65536);
    STAGE(A, brow, 0, 0, 0);
    STAGE(A, brow, 1, 0, 0);
    STAGE(B, bcol, 0, 1, 65536 + 32768);
    STAGE(B, bcol, 1, 1, 65536 + 32768);
    asm volatile("s_waitcnt vmcnt(4)" ::: "memory");   // B(0),A(0) resident; B(1) in flight
    __builtin_amdgcn_s_barrier();
    RD4(B0a, lds + 65536 + rbB, 0, slot0);
    RD4(Aaa, lds + rbA,         0, slot0);

    // Per tile t (buffer c = t&1), phases (operands prefetched one phase ahead):
    //  P1: stage A(t+1)->c^1; read A[m4-7,kk0]; lgkm(4); MFMA(m0-3,kk0)
    //  P2: read B[kk1]+A[m0-3,kk1]; lgkm(8);            MFMA(m4-7,kk0)
    //  P3: read A[m4-7,kk1]; lgkm(4);                   MFMA(m0-3,kk1); BARRIER
    //  P4: stage B(t+2)->c; vmcnt(4); BARRIER;
    //      read B[kk0]+A[m0-3,kk0] of t+1 from c^1; lgkm(8); MFMA(m4-7,kk1); BARRIER
#define TILE(T_, B0in, Aain, B0out, Aaout)                                          \
    {                                                                               \
        const int t_ = (T_);                                                        \
        const int c_ = t_ & 1;                                                      \
        const char* bA_  = lds + c_ * 32768 + rbA;                                  \
        const char* bB_  = lds + 65536 + c_ * 32768 + rbB;                          \
        const char* bAn_ = lds + (c_ ^ 1) * 32768 + rbA;                            \
        const char* bBn_ = lds + 65536 + (c_ ^ 1) * 32768 + rbB;                    \
        short8 B1f[4], Abf[4], Acf[4], Adf[4];                                      \
        /* P1 */                                                                    \
        if (t_ + 1 < T_TILES) {                                                     \
            STAGE(A, brow, 0, t_ + 1, (c_ ^ 1) * 32768);                            \
            STAGE(A, brow, 1, t_ + 1, (c_ ^ 1) * 32768);                            \
        }                                                                           \
        RD4(Abf, bA_, 4, slot0);                                                    \
        asm volatile("s_waitcnt lgkmcnt(4)" ::: "memory");                          \
        __builtin_amdgcn_s_setprio(1);                                              \
        MFMA16(0, B0in, Aain);                                                      \
        __builtin_amdgcn_s_setprio(0);                                              \
        /* P2 */                                                                    \
        RD4(B1f, bB_, 0, slot1);                                                    \
        RD4(Acf, bA_, 0, slot1);                                                    \
        asm volatile("s_waitcnt lgkmcnt(8)" ::: "memory");                          \
        __builtin_amdgcn_s_setprio(1);                                              \
        MFMA16(4, B0in, Abf);                                                       \
        __builtin_amdgcn_s_setprio(0);                                              \
        /* P3 */                                                                    \
        RD4(Adf, bA_, 4, slot1);                                                    \
        asm volatile("s_waitcnt lgkmcnt(4)" ::: "memory");                          \
        __builtin_amdgcn_s_setprio(1);                                              \
        MFMA16(0, B1f, Acf);                                                        \
        __builtin_amdgcn_s_setprio(0);                                              \
        __builtin_amdgcn_s_barrier();                                               \
        /* P4 */                                                                    \
        if (t_ + 2 < T_TILES) {                                                     \
            STAGE(B, bcol, 0, t_ + 2, 65536 + c_ * 32768);                          \
            STAGE(B, bcol, 1, t_ + 2, 65536 + c_ * 32768);                          \
            asm volatile("s_waitcnt vmcnt(4)" ::: "memory");                        \
        } else if (t_ + 1 < T_TILES) {                                              \
            asm volatile("s_waitcnt vmcnt(0)" ::: "memory");                        \
        }                                                                           \
        __builtin_amdgcn_s_barrier();                                               \
        if (t_ + 1 < T_TILES) {                                                     \
            RD4(B0out, bBn_, 0, slot0);                                             \
            RD4(Aaout, bAn_, 0, slot0);                                             \
            asm volatile("s_waitcnt lgkmcnt(8)" ::: "memory");                      \
        } else {                                                                    \
            asm volatile("s_waitcnt lgkmcnt(0)" ::: "memory");                      \
        }                                                                           \
        __builtin_amdgcn_s_setprio(1);                                              \
        MFMA16(4, B1f, Adf);                                                        \
        __builtin_amdgcn_s_setprio(0);                                              \
        __builtin_amdgcn_s_barrier();                                               \
    }

    for (int tt = 0; tt < T_TILES; tt += 2) {
        TILE(tt,     B0a, Aaa, B0b, Aab);
        TILE(tt + 1, B0b, Aab, B0a, Aaa);
    }

    // epilogue: C/D frag layout col = lane&15, row = hi*4 + reg
    const int col   = lane & 15;
    const int rbase = hi * 4;
    float bv[4];
#pragma unroll
    for (int n = 0; n < 4; ++n)
        bv[n] = bias[bcol + wn * 64 + n * 16 + col];

#pragma unroll
    for (int m = 0; m < 8; ++m) {
        const int mrow = brow + wm * 128 + m * 16 + rbase;
#pragma unroll
        for (int r = 0; r < 4; ++r) {
            float* crow = C + (size_t)(mrow + r) * N_DIM + bcol + wn * 64 + col;
#pragma unroll
            for (int n = 0; n < 4; ++n)
                crow[n * 16] = acc[m][n][r] + bv[n];
        }
    }
#undef STAGE
#undef MFMA16
#undef RD4
#undef TILE
}

extern "C" void kernel_launch(void* const* d_in, const int* in_sizes, int n_in,
                              void* d_out, int out_size, void* d_ws, size_t ws_size,
                              hipStream_t stream) {
    const float* x         = (const float*)d_in[0];
    const float* weight    = (const float*)d_in[1];
    const float* bias      = (const float*)d_in[2];
    const float* value     = (const float*)d_in[3];
    const float* min_scale = (const float*)d_in[4];
    const float* max_scale = (const float*)d_in[5];
    float* out = (float*)d_out;

    __hip_bfloat16* xb  = (__hip_bfloat16*)d_ws;                       // [M][K] bf16
    __hip_bfloat16* wqb = xb + (size_t)M_DIM * K_DIM;                  // [N][K] bf16

    quant_kernel<<<(N_DIM * K_DIM / GROUPSZ) / 4, 256, 0, stream>>>(
        weight, value, min_scale, max_scale, wqb);
    cast_kernel<<<(M_DIM * K_DIM) / (256 * 8), 256, 0, stream>>>(x, xb);
    gemm_kernel<<<(M_DIM / BM) * (N_DIM / BN), 512, 0, stream>>>(xb, wqb, bias, out);
}

// Round 6
// 167.857 us; speedup vs baseline: 2.9886x; 2.9886x over previous
//
#include <hip/hip_runtime.h>
#include <hip/hip_bf16.h>
#include <hip/hip_fp16.h>
#include <stdint.h>

#define M_DIM 4096   // B*S = 2*2048
#define N_DIM 4096   // O
#define K_DIM 4096   // I
#define GROUPSZ 128
#define MAXQ 15.0f

#define BM 256
#define BN 256
#define BK 64
#define T_TILES (K_DIM / BK)   // 64

typedef __attribute__((ext_vector_type(8))) short short8;
typedef __attribute__((ext_vector_type(4))) float f32x4;

// ---------------- quant: groupwise asymmetric fake-quant, f32 -> bf16 ----------------
__global__ __launch_bounds__(256) void quant_kernel(
    const float* __restrict__ weight, const float* __restrict__ value,
    const float* __restrict__ min_scale, const float* __restrict__ max_scale,
    __hip_bfloat16* __restrict__ wq)
{
    const int tid  = threadIdx.x;
    const int wave = tid >> 6;
    const int lane = tid & 63;
    const long g    = (long)blockIdx.x * 4 + wave;
    const long base = g * GROUPSZ + lane * 2;

    const float2 w = *(const float2*)(weight + base);
    const float2 v = *(const float2*)(value  + base);

    float mn = fminf(w.x, w.y);
    float mx = fmaxf(w.x, w.y);
#pragma unroll
    for (int off = 32; off >= 1; off >>= 1) {
        mn = fminf(mn, __shfl_xor(mn, off, 64));
        mx = fmaxf(mx, __shfl_xor(mx, off, 64));
    }
    mn = fminf(mn, 0.0f);
    mx = fmaxf(mx, 0.0f);

    const float ms = fminf(fmaxf(min_scale[g], -1.0f), 0.0f) + 1.0f;
    const float xs = fminf(fmaxf(max_scale[g], -1.0f), 0.0f) + 1.0f;
    float wmin = mn * ms;
    float wmax = mx * xs;
    if (wmin == 0.0f && wmax == 0.0f) { wmin = -1.0f; wmax = 1.0f; }

    const float scale = (float)(_Float16)((wmax - wmin) / MAXQ);
    const float zp    = rintf(-wmin / scale);

    const float q0 = fminf(fmaxf(rintf(w.x / scale + v.x) + zp, 0.0f), MAXQ);
    const float q1 = fminf(fmaxf(rintf(w.y / scale + v.y) + zp, 0.0f), MAXQ);
    const float o0 = scale * (q0 - zp);
    const float o1 = scale * (q1 - zp);

    __hip_bfloat162 o;
    o.x = __float2bfloat16(o0);
    o.y = __float2bfloat16(o1);
    *(__hip_bfloat162*)(wq + base) = o;
}

// ---------------- x cast: f32 -> bf16, 8 elems/thread ----------------
__global__ __launch_bounds__(256) void cast_kernel(
    const float* __restrict__ x, __hip_bfloat16* __restrict__ xb)
{
    const long i = ((long)blockIdx.x * 256 + threadIdx.x) * 8;
    const float4 a = *(const float4*)(x + i);
    const float4 b = *(const float4*)(x + i + 4);
    union { short8 s; __hip_bfloat16 h[8]; } u;
    u.h[0] = __float2bfloat16(a.x);
    u.h[1] = __float2bfloat16(a.y);
    u.h[2] = __float2bfloat16(a.z);
    u.h[3] = __float2bfloat16(a.w);
    u.h[4] = __float2bfloat16(b.x);
    u.h[5] = __float2bfloat16(b.y);
    u.h[6] = __float2bfloat16(b.z);
    u.h[7] = __float2bfloat16(b.w);
    *(short8*)(xb + i) = u.s;
}

// ---------------- GEMM: 256x256, BK=64, 8 waves, 1-barrier/tile read-chain ----------------
// C[m][n] = sum_k A[m][k]*B[n][k] + bias[n]
// Per tile: [vmcnt(0); barrier] then a single read->MFMA chain with counted
// lgkmcnt waits (never 0 until the last cluster) so ds_reads drain UNDER the
// MFMA clusters. All staging targets the other buffer, issued at tile top.
__global__ __launch_bounds__(512, 2) void gemm_kernel(
    const __hip_bfloat16* __restrict__ A,   // [M][K] bf16 (x)
    const __hip_bfloat16* __restrict__ B,   // [N][K] bf16 (wq)
    const float* __restrict__ bias,
    float* __restrict__ C)                  // [M][N] f32
{
    __shared__ __align__(16) char lds[131072];
    // A buf c: [c*32768, +32768); B buf c: [65536 + c*32768, +32768)
    // row r at r*128 bytes; 16B slot s holds logical slot s ^ (r&7).

    const int tid  = threadIdx.x;
    const int lane = tid & 63;
    const int wv   = tid >> 6;
    const int wm   = wv >> 2;          // 2 (M) x 4 (N) wave grid
    const int wn   = wv & 3;

    const int bid = blockIdx.x;
    const int swz = (bid & 7) * (gridDim.x >> 3) + (bid >> 3);
    const int brow = (swz >> 4) * BM;
    const int bcol = (swz & 15) * BN;

    const int stg_r = tid >> 3;
    const int cc    = ((tid & 7) ^ (stg_r & 7)) * 8;

#define STAGE(XP, rowbase, h, tau, ldsbase)                                         \
    { _Pragma("unroll")                                                             \
      for (int inst = 0; inst < 2; ++inst) {                                        \
        const __hip_bfloat16* g = (XP) +                                            \
            (size_t)((rowbase) + (h) * 128 + inst * 64 + stg_r) * K_DIM +           \
            (tau) * 64 + cc;                                                        \
        __builtin_amdgcn_global_load_lds(                                           \
            (const __attribute__((address_space(1))) void*)g,                       \
            (__attribute__((address_space(3))) void*)(lds + (ldsbase) +             \
                (h) * 16384 + inst * 8192 + (wv << 10)),                            \
            16, 0, 0);                                                              \
      } }

    const int ro = lane & 15;
    const int hi = lane >> 4;
    const int slot0 = ((0 + hi) ^ (ro & 7)) << 4;
    const int slot1 = ((4 + hi) ^ (ro & 7)) << 4;
    const int rbA = (wm * 128 + ro) * 128;
    const int rbB = (wn * 64  + ro) * 128;

    f32x4 acc[8][4] = {};

    // 16 MFMA: rows M0,M0+1 x 4 N x 2 kk, kk-outer (dep distance 8)
#define MFMA16(M0, X0, X1)                                                          \
    { _Pragma("unroll")                                                             \
      for (int n = 0; n < 4; ++n) {                                                 \
        acc[M0][n]     = __builtin_amdgcn_mfma_f32_16x16x32_bf16((X0)[0], bfr[n][0], acc[M0][n],     0, 0, 0); \
        acc[M0 + 1][n] = __builtin_amdgcn_mfma_f32_16x16x32_bf16((X1)[0], bfr[n][0], acc[M0 + 1][n], 0, 0, 0); \
      }                                                                             \
      _Pragma("unroll")                                                             \
      for (int n = 0; n < 4; ++n) {                                                 \
        acc[M0][n]     = __builtin_amdgcn_mfma_f32_16x16x32_bf16((X0)[1], bfr[n][1], acc[M0][n],     0, 0, 0); \
        acc[M0 + 1][n] = __builtin_amdgcn_mfma_f32_16x16x32_bf16((X1)[1], bfr[n][1], acc[M0 + 1][n], 0, 0, 0); \
      } }

#define LDA2(dst, m)                                                                \
    dst[0] = *(const short8*)(bA + (m) * 2048 + slot0);                             \
    dst[1] = *(const short8*)(bA + (m) * 2048 + slot1);

    // prologue: stage tile 0 into buffer 0
    STAGE(B, bcol, 0, 0, 65536);
    STAGE(B, bcol, 1, 0, 65536);
    STAGE(A, brow, 0, 0, 0);
    STAGE(A, brow, 1, 0, 0);

#pragma unroll 1
    for (int t = 0; t < T_TILES; ++t) {
        const int c = t & 1;
        const char* bA = lds + c * 32768 + rbA;
        const char* bB = lds + 65536 + c * 32768 + rbB;

        // tile boundary: own staging loads done, then all waves' loads done
        asm volatile("s_waitcnt vmcnt(0)" ::: "memory");
        __builtin_amdgcn_s_barrier();

        short8 bfr[4][2];
        short8 a0[2][2], a1[2][2], a2[2][2], a3[2][2];

        // top burst: all B (8) + A m0,m1 (4)
#pragma unroll
        for (int n = 0; n < 4; ++n) {
            bfr[n][0] = *(const short8*)(bB + n * 2048 + slot0);
            bfr[n][1] = *(const short8*)(bB + n * 2048 + slot1);
        }
        LDA2(a0[0], 0); LDA2(a0[1], 1);

        // stage next tile into the other buffer (vmcnt traffic only)
        if (t + 1 < T_TILES) {
            STAGE(A, brow, 0, t + 1, (c ^ 1) * 32768);
            STAGE(A, brow, 1, t + 1, (c ^ 1) * 32768);
            STAGE(B, bcol, 0, t + 1, 65536 + (c ^ 1) * 32768);
            STAGE(B, bcol, 1, t + 1, 65536 + (c ^ 1) * 32768);
        }

        // chained reads: each cluster's operands were issued one cluster early;
        // counted lgkmcnt leaves the newest 4 reads in flight under the MFMAs.
        LDA2(a1[0], 2); LDA2(a1[1], 3);
        asm volatile("s_waitcnt lgkmcnt(4)" ::: "memory");   // B,a0 done
        __builtin_amdgcn_sched_barrier(0);
        __builtin_amdgcn_s_setprio(1);
        MFMA16(0, a0[0], a0[1]);
        __builtin_amdgcn_s_setprio(0);

        LDA2(a2[0], 4); LDA2(a2[1], 5);
        asm volatile("s_waitcnt lgkmcnt(4)" ::: "memory");   // a1 done
        __builtin_amdgcn_sched_barrier(0);
        __builtin_amdgcn_s_setprio(1);
        MFMA16(2, a1[0], a1[1]);
        __builtin_amdgcn_s_setprio(0);

        LDA2(a3[0], 6); LDA2(a3[1], 7);
        asm volatile("s_waitcnt lgkmcnt(4)" ::: "memory");   // a2 done
        __builtin_amdgcn_sched_barrier(0);
        __builtin_amdgcn_s_setprio(1);
        MFMA16(4, a2[0], a2[1]);
        __builtin_amdgcn_s_setprio(0);

        asm volatile("s_waitcnt lgkmcnt(0)" ::: "memory");   // a3 done
        __builtin_amdgcn_sched_barrier(0);
        __builtin_amdgcn_s_setprio(1);
        MFMA16(6, a3[0], a3[1]);
        __builtin_amdgcn_s_setprio(0);
    }

    // epilogue: C/D frag layout col = lane&15, row = hi*4 + reg
    const int col   = lane & 15;
    const int rbase = hi * 4;
    float bv[4];
#pragma unroll
    for (int n = 0; n < 4; ++n)
        bv[n] = bias[bcol + wn * 64 + n * 16 + col];

#pragma unroll
    for (int m = 0; m < 8; ++m) {
        const int mrow = brow + wm * 128 + m * 16 + rbase;
#pragma unroll
        for (int r = 0; r < 4; ++r) {
            float* crow = C + (size_t)(mrow + r) * N_DIM + bcol + wn * 64 + col;
#pragma unroll
            for (int n = 0; n < 4; ++n)
                crow[n * 16] = acc[m][n][r] + bv[n];
        }
    }
#undef STAGE
#undef MFMA16
#undef LDA2
}

extern "C" void kernel_launch(void* const* d_in, const int* in_sizes, int n_in,
                              void* d_out, int out_size, void* d_ws, size_t ws_size,
                              hipStream_t stream) {
    const float* x         = (const float*)d_in[0];
    const float* weight    = (const float*)d_in[1];
    const float* bias      = (const float*)d_in[2];
    const float* value     = (const float*)d_in[3];
    const float* min_scale = (const float*)d_in[4];
    const float* max_scale = (const float*)d_in[5];
    float* out = (float*)d_out;

    __hip_bfloat16* xb  = (__hip_bfloat16*)d_ws;                       // [M][K] bf16
    __hip_bfloat16* wqb = xb + (size_t)M_DIM * K_DIM;                  // [N][K] bf16

    quant_kernel<<<(N_DIM * K_DIM / GROUPSZ) / 4, 256, 0, stream>>>(
        weight, value, min_scale, max_scale, wqb);
    cast_kernel<<<(M_DIM * K_DIM) / (256 * 8), 256, 0, stream>>>(x, xb);
    gemm_kernel<<<(M_DIM / BM) * (N_DIM / BN), 512, 0, stream>>>(xb, wqb, bias, out);
}